// Round 4
// baseline (534.458 us; speedup 1.0000x reference)
//
#include <hip/hip_runtime.h>
#include <hip/hip_bf16.h>

// Problem constants: N=20000 nodes, K=32 nbrs, C=128, H=256
#define NN    20000
#define KNN   32
#define CIN   128
#define HD    256
#define EE    (NN * KNN)        // 640000 edges
#define MT    128               // edge rows per tile = 4 full nodes
#define LSTR  264               // LDS row stride (bf16 elems), 256+8 pad
#define TPB   5                 // tiles per block -> block covers 640 edges / 20 nodes
#define NBLK  (EE / (MT * TPB)) // 1000 blocks

typedef __bf16 bf16x8_t __attribute__((ext_vector_type(8)));
typedef __bf16 bf16x4_t __attribute__((ext_vector_type(4)));
typedef float  f32x4_t  __attribute__((ext_vector_type(4)));

// Prep: (a) cast nf -> bf16 nfb; (b) W1' = [W1a - W1b ; W1b] transposed to [n][k] bf16;
// (c) W2 transposed to [n][k] bf16.  E' = [x_v | x_vp] then E'@W1' == concat(xv, xp-xv)@W1.
__global__ void ec_prep(const float* __restrict__ nf, const float* __restrict__ W1,
                        const float* __restrict__ W2, __bf16* __restrict__ nfb,
                        __bf16* __restrict__ W1T, __bf16* __restrict__ W2T) {
    int bid = blockIdx.x;
    if (bid < (NN * CIN) / 256) {                    // 10000 blocks: nf cast
        int idx = bid * 256 + threadIdx.x;
        nfb[idx] = (__bf16)nf[idx];
    } else {                                         // 256 blocks: weights
        int idx = (bid - (NN * CIN) / 256) * 256 + threadIdx.x;   // 0..65535
        int k = idx >> 8, n = idx & 255;
        float w1 = (k < CIN) ? (W1[k * 256 + n] - W1[(k + CIN) * 256 + n])
                             : W1[k * 256 + n];
        W1T[n * 256 + k] = (__bf16)w1;
        W2T[n * 256 + k] = (__bf16)W2[k * 256 + n];
    }
}

// M=128 tile; single 66KB LDS buffer aliased E-then-H; 2 blocks/CU.
// Sender rows register-prefetched one tile ahead (indices preloaded at block start).
__global__ __launch_bounds__(256, 2) void ec_main(
    const __bf16* __restrict__ nfb,      // [NN][CIN] bf16
    const int*   __restrict__ senders,   // [EE]
    const __bf16* __restrict__ W1T,      // [256 n][256 k]
    const __bf16* __restrict__ W2T,      // [256 n][256 k]
    const float* __restrict__ b1,
    const float* __restrict__ b2,
    float* __restrict__ out)             // [NN][HD] fp32
{
    __shared__ __bf16 sB[MT * LSTR];     // E' tile, then H tile (aliased)

    const int tid  = threadIdx.x;
    const int lane = tid & 63;
    const int wave = tid >> 6;
    const int qrow = lane >> 4;
    const int lcol = lane & 15;
    const int blk  = blockIdx.x;
    const int srow  = tid >> 1;          // staging: edge row 0..127 (2 threads/row)
    const int spart = tid & 1;           // staging: which 64-elem half of a 128-elem row

    // preload sender indices for all tiles (removes dependent-load hop from gather)
    int sidx[TPB];
#pragma unroll
    for (int t = 0; t < TPB; ++t)
        sidx[t] = senders[(blk * TPB + t) * MT + srow];

    // gather tile 0 sender chunk into regs, then write E'0 = [x_v | x_vp]
    bf16x8_t gu[8];
    {
        const bf16x8_t* ur = (const bf16x8_t*)(nfb + (size_t)sidx[0] * CIN + spart * 64);
#pragma unroll
        for (int i = 0; i < 8; ++i) gu[i] = ur[i];
        int node = (blk * TPB) * 4 + (srow >> 5);
        const bf16x8_t* vr = (const bf16x8_t*)(nfb + (size_t)node * CIN + spart * 64);
        __bf16* p = sB + srow * LSTR + spart * 64;
#pragma unroll
        for (int i = 0; i < 8; ++i) {
            *(bf16x8_t*)(p + i * 8)       = vr[i];
            *(bf16x8_t*)(p + CIN + i * 8) = gu[i];
        }
    }
    __syncthreads();

    for (int t = 0; t < TPB; ++t) {
        // ---- issue sender gather for tile t+1 (in flight across both GEMMs) ----
        if (t + 1 < TPB) {
            const bf16x8_t* ur = (const bf16x8_t*)(nfb + (size_t)sidx[t + 1] * CIN + spart * 64);
#pragma unroll
            for (int i = 0; i < 8; ++i) gu[i] = ur[i];
        }

        // ---- GEMM1 (swapped): D = W1'slice · E'^T ; acc1[mi<4][ni<8] ----
        f32x4_t acc1[4][8];
#pragma unroll
        for (int mi = 0; mi < 4; ++mi)
#pragma unroll
            for (int ni = 0; ni < 8; ++ni)
                acc1[mi][ni] = (f32x4_t){0.f, 0.f, 0.f, 0.f};
#pragma unroll
        for (int kt = 0; kt < 8; ++kt) {
            bf16x8_t wf[4], ef[8];
#pragma unroll
            for (int mi = 0; mi < 4; ++mi) {
                int n = wave * 64 + mi * 16 + lcol;
                wf[mi] = *(const bf16x8_t*)(W1T + n * 256 + kt * 32 + qrow * 8);
            }
#pragma unroll
            for (int ni = 0; ni < 8; ++ni)
                ef[ni] = *(const bf16x8_t*)(sB + (ni * 16 + lcol) * LSTR + kt * 32 + qrow * 8);
#pragma unroll
            for (int mi = 0; mi < 4; ++mi)
#pragma unroll
                for (int ni = 0; ni < 8; ++ni)
                    acc1[mi][ni] = __builtin_amdgcn_mfma_f32_16x16x32_bf16(
                        wf[mi], ef[ni], acc1[mi][ni], 0, 0, 0);
        }
        __syncthreads();   // all waves done reading E' before overwriting with H

        // ---- epilogue 1: +b1, relu, packed bf16x4 -> sB (H layout [edge][feature]) ----
#pragma unroll
        for (int mi = 0; mi < 4; ++mi) {
            int fbase = wave * 64 + mi * 16 + qrow * 4;
            float4 bb = *(const float4*)(b1 + fbase);
#pragma unroll
            for (int ni = 0; ni < 8; ++ni) {
                int m = ni * 16 + lcol;
                float v0 = acc1[mi][ni][0] + bb.x;
                float v1 = acc1[mi][ni][1] + bb.y;
                float v2 = acc1[mi][ni][2] + bb.z;
                float v3 = acc1[mi][ni][3] + bb.w;
                bf16x4_t h = { (__bf16)fmaxf(v0, 0.f), (__bf16)fmaxf(v1, 0.f),
                               (__bf16)fmaxf(v2, 0.f), (__bf16)fmaxf(v3, 0.f) };
                *(bf16x4_t*)(sB + m * LSTR + fbase) = h;
            }
        }
        __syncthreads();

        // ---- GEMM2 (unswapped): D = H · W2slice ; acc2[mi<8][ni<4] ----
        f32x4_t acc2[8][4];
#pragma unroll
        for (int mi = 0; mi < 8; ++mi)
#pragma unroll
            for (int ni = 0; ni < 4; ++ni)
                acc2[mi][ni] = (f32x4_t){0.f, 0.f, 0.f, 0.f};
#pragma unroll
        for (int kt = 0; kt < 8; ++kt) {
            bf16x8_t af[8], wf[4];
#pragma unroll
            for (int mi = 0; mi < 8; ++mi)
                af[mi] = *(const bf16x8_t*)(sB + (mi * 16 + lcol) * LSTR + kt * 32 + qrow * 8);
#pragma unroll
            for (int ni = 0; ni < 4; ++ni) {
                int n = wave * 64 + ni * 16 + lcol;
                wf[ni] = *(const bf16x8_t*)(W2T + n * 256 + kt * 32 + qrow * 8);
            }
#pragma unroll
            for (int mi = 0; mi < 8; ++mi)
#pragma unroll
                for (int ni = 0; ni < 4; ++ni)
                    acc2[mi][ni] = __builtin_amdgcn_mfma_f32_16x16x32_bf16(
                        af[mi], wf[ni], acc2[mi][ni], 0, 0, 0);
        }

        // ---- epilogue 2: per-node max over 32 edge rows, +b2, store ----
        int g4 = (blk * TPB + t) * 4;
#pragma unroll
        for (int ni = 0; ni < 4; ++ni) {
            int col = wave * 64 + ni * 16 + lcol;
#pragma unroll
            for (int node = 0; node < 4; ++node) {
                float mx = -3.402823466e38f;
#pragma unroll
                for (int h = 0; h < 2; ++h)
#pragma unroll
                    for (int r = 0; r < 4; ++r)
                        mx = fmaxf(mx, acc2[node * 2 + h][ni][r]);
                mx = fmaxf(mx, __shfl_xor(mx, 16, 64));
                mx = fmaxf(mx, __shfl_xor(mx, 32, 64));
                if (qrow == 0)
                    out[(size_t)(g4 + node) * HD + col] = mx + b2[col];
            }
        }

        __syncthreads();   // all waves done reading H before writing next E'

        // ---- write E'(t+1): receiver rows loaded fresh (L2-hot, sequential nodes) ----
        if (t + 1 < TPB) {
            int node = (blk * TPB + t + 1) * 4 + (srow >> 5);
            const bf16x8_t* vr = (const bf16x8_t*)(nfb + (size_t)node * CIN + spart * 64);
            __bf16* p = sB + srow * LSTR + spart * 64;
#pragma unroll
            for (int i = 0; i < 8; ++i) {
                *(bf16x8_t*)(p + i * 8)       = vr[i];
                *(bf16x8_t*)(p + CIN + i * 8) = gu[i];
            }
        }
        __syncthreads();
    }
}

extern "C" void kernel_launch(void* const* d_in, const int* in_sizes, int n_in,
                              void* d_out, int out_size, void* d_ws, size_t ws_size,
                              hipStream_t stream) {
    const float* nf      = (const float*)d_in[0];
    const int*   senders = (const int*)d_in[1];
    // d_in[2] = receivers: implicit (repeat(arange(N), K)), unused
    const float* W1 = (const float*)d_in[3];
    const float* b1 = (const float*)d_in[4];
    const float* W2 = (const float*)d_in[5];
    const float* b2 = (const float*)d_in[6];

    __bf16* W1T = (__bf16*)d_ws;                 // 128 KB
    __bf16* W2T = W1T + 256 * 256;               // 128 KB
    __bf16* nfb = W2T + 256 * 256;               // 20000*128*2 = 5.12 MB

    ec_prep<<<(NN * CIN) / 256 + 256, 256, 0, stream>>>(nf, W1, W2, nfb, W1T, W2T);
    ec_main<<<NBLK, 256, 0, stream>>>(nfb, senders, W1T, W2T, b1, b2, (float*)d_out);
}

// Round 5
// 334.209 us; speedup vs baseline: 1.5992x; 1.5992x over previous
//
#include <hip/hip_runtime.h>
#include <hip/hip_bf16.h>

// Problem constants: N=20000 nodes, K=32 nbrs, C=128, H=256
#define NN    20000
#define KNN   32
#define CIN   128
#define HD    256
#define EE    (NN * KNN)        // 640000 edges
#define MT    64                // edge rows per tile = 2 full nodes
#define TPB   10                // tiles per block
#define NBLK  (EE / (MT * TPB)) // 1000 blocks

typedef __bf16 bf16x8_t __attribute__((ext_vector_type(8)));
typedef __bf16 bf16x4_t __attribute__((ext_vector_type(4)));
typedef float  f32x4_t  __attribute__((ext_vector_type(4)));

// Prep:
//  (a) nfb = bf16(nf)                                         [10000 blocks]
//  (b) w1g = frag-ordered W1' where W1' = [W1a-W1b ; W1b]     [256 blocks]
//      chunk (kt,qr) holds rows n=0..255 x 8 k-elems: w1g[((kt*4+qr)*256+n)*8+j]
//      (E' = [x_v | x_vp], E'@W1' == concat(xv, xp-xv)@W1)
//  (c) w2t[n*256+k] = bf16(W2[k][n])  (n-major for register fragments)
__global__ void ec_prep(const float* __restrict__ nf, const float* __restrict__ W1,
                        const float* __restrict__ W2, __bf16* __restrict__ nfb,
                        __bf16* __restrict__ w1g, __bf16* __restrict__ w2t) {
    int bid = blockIdx.x;
    if (bid < (NN * CIN) / 256) {
        int i = bid * 256 + threadIdx.x;
        nfb[i] = (__bf16)nf[i];
    } else {
        int idx = (bid - (NN * CIN) / 256) * 256 + threadIdx.x;   // 0..65535
        int k = idx >> 8, n = idx & 255;
        float v = (k < CIN) ? (W1[k * 256 + n] - W1[(k + CIN) * 256 + n])
                            : W1[k * 256 + n];
        int kt = k >> 5, qr = (k >> 3) & 3, j = k & 7;
        w1g[(size_t)((kt * 4 + qr) * 256 + n) * 8 + j] = (__bf16)v;
        w2t[n * 256 + k] = (__bf16)W2[k * 256 + n];
    }
}

// Weight-stationary: W1' kt1..7 in LDS (112 KB frag-ordered), kt0 + all of W2
// in registers; E loaded direct global->fragment regs (recv = broadcast,
// sender = prefetched one tile ahead); only H round-trips LDS (32 KB).
__global__ __launch_bounds__(256, 1) void ec_main(
    const __bf16* __restrict__ nfb,      // [NN][CIN] bf16
    const int*   __restrict__ senders,   // [EE]
    const __bf16* __restrict__ w1g,      // frag-ordered W1' (65536)
    const __bf16* __restrict__ w2t,      // [256 n][256 k]
    const float* __restrict__ b1,
    const float* __restrict__ b2,
    float* __restrict__ out)             // [NN][HD] fp32
{
    __shared__ __attribute__((aligned(16))) __bf16 ldsW1[57344];  // 112 KB: kt 1..7
    __shared__ __attribute__((aligned(16))) __bf16 ldsH[16384];   // 32 KB frag-ordered H

    const int tid  = threadIdx.x;
    const int lane = tid & 63;
    const int wave = tid >> 6;
    const int qrow = lane >> 4;
    const int lcol = lane & 15;
    const int blk  = blockIdx.x;

    // ---- copy frag-ordered W1' chunks kt=1..7 into LDS (contiguous 114688 B) ----
    {
        const float4* src = (const float4*)(w1g + 8192);
        float4* dst = (float4*)ldsW1;
#pragma unroll
        for (int i = 0; i < 28; ++i)
            dst[i * 256 + tid] = src[i * 256 + tid];
    }

    // ---- register-resident weights ----
    bf16x8_t w10[4];                       // W1' kt=0 fragments
#pragma unroll
    for (int mi = 0; mi < 4; ++mi)
        w10[mi] = *(const bf16x8_t*)(w1g + (size_t)(qrow * 256 + wave * 64 + mi * 16 + lcol) * 8);

    bf16x8_t w2f[8][4];                    // full W2 slice: 128 VGPRs
#pragma unroll
    for (int kt = 0; kt < 8; ++kt)
#pragma unroll
        for (int ni = 0; ni < 4; ++ni)
            w2f[kt][ni] = *(const bf16x8_t*)(w2t + (size_t)(wave * 64 + ni * 16 + lcol) * 256
                                                 + kt * 32 + qrow * 8);

    float4 bias1[4];
#pragma unroll
    for (int mi = 0; mi < 4; ++mi)
        bias1[mi] = *(const float4*)(b1 + wave * 64 + mi * 16 + qrow * 4);
    float bias2[4];
#pragma unroll
    for (int ni = 0; ni < 4; ++ni)
        bias2[ni] = b2[wave * 64 + ni * 16 + lcol];

    // ---- tile-0 sender indices + sender fragments (B-frag layout, cols 128..255) ----
    int sidx[4];
#pragma unroll
    for (int ni = 0; ni < 4; ++ni)
        sidx[ni] = senders[blk * TPB * MT + ni * 16 + lcol];
    bf16x8_t sf[4][4];                     // [ni][kt-4]
#pragma unroll
    for (int ni = 0; ni < 4; ++ni)
#pragma unroll
        for (int c = 0; c < 4; ++c)
            sf[ni][c] = *(const bf16x8_t*)(nfb + (size_t)sidx[ni] * CIN + c * 32 + qrow * 8);

    __syncthreads();   // ldsW1 ready

#pragma unroll 1
    for (int t = 0; t < TPB; ++t) {
        const int node0 = (blk * TPB + t) * 2;

        // early-issue next tile's sender indices
        const int tn = (t + 1 < TPB) ? t + 1 : t;
        int nsidx[4];
#pragma unroll
        for (int ni = 0; ni < 4; ++ni)
            nsidx[ni] = senders[(blk * TPB + tn) * MT + ni * 16 + lcol];

        // receiver fragments kt 0..3: broadcast (all edges of a node share x_v)
        bf16x8_t efr[2][4];
#pragma unroll
        for (int nd = 0; nd < 2; ++nd)
#pragma unroll
            for (int c = 0; c < 4; ++c)
                efr[nd][c] = *(const bf16x8_t*)(nfb + (size_t)(node0 + nd) * CIN + c * 32 + qrow * 8);

        // ---- GEMM1 (swapped): D = W1'slice · E'^T ; acc[feat-group][edge-group] ----
        f32x4_t acc[4][4];
#pragma unroll
        for (int mi = 0; mi < 4; ++mi)
#pragma unroll
            for (int ni = 0; ni < 4; ++ni)
                acc[mi][ni] = (f32x4_t){0.f, 0.f, 0.f, 0.f};

        // kt = 0: W1 from registers
#pragma unroll
        for (int mi = 0; mi < 4; ++mi)
#pragma unroll
            for (int ni = 0; ni < 4; ++ni)
                acc[mi][ni] = __builtin_amdgcn_mfma_f32_16x16x32_bf16(
                    w10[mi], efr[ni >> 1][0], acc[mi][ni], 0, 0, 0);
        // kt = 1..3: W1 from LDS, E = receiver broadcast
#pragma unroll
        for (int kt = 1; kt < 4; ++kt) {
            bf16x8_t wf[4];
#pragma unroll
            for (int mi = 0; mi < 4; ++mi)
                wf[mi] = *(const bf16x8_t*)(ldsW1 +
                    (size_t)(((kt - 1) * 4 + qrow) * 256 + wave * 64 + mi * 16 + lcol) * 8);
#pragma unroll
            for (int mi = 0; mi < 4; ++mi)
#pragma unroll
                for (int ni = 0; ni < 4; ++ni)
                    acc[mi][ni] = __builtin_amdgcn_mfma_f32_16x16x32_bf16(
                        wf[mi], efr[ni >> 1][kt], acc[mi][ni], 0, 0, 0);
        }
        // kt = 4..7: W1 from LDS, E = prefetched sender fragments
#pragma unroll
        for (int kt = 4; kt < 8; ++kt) {
            bf16x8_t wf[4];
#pragma unroll
            for (int mi = 0; mi < 4; ++mi)
                wf[mi] = *(const bf16x8_t*)(ldsW1 +
                    (size_t)(((kt - 1) * 4 + qrow) * 256 + wave * 64 + mi * 16 + lcol) * 8);
#pragma unroll
            for (int mi = 0; mi < 4; ++mi)
#pragma unroll
                for (int ni = 0; ni < 4; ++ni)
                    acc[mi][ni] = __builtin_amdgcn_mfma_f32_16x16x32_bf16(
                        wf[mi], sf[ni][kt - 4], acc[mi][ni], 0, 0, 0);
        }

        __syncthreads();   // barrier A: previous tile's GEMM2 done reading ldsH

        // ---- epilogue 1: +b1, relu, packed bf16x4 -> ldsH (frag-ordered) ----
#pragma unroll
        for (int mi = 0; mi < 4; ++mi) {
            const int f0  = wave * 64 + mi * 16 + qrow * 4;
            const int ktp = f0 >> 5, qrp = (f0 >> 3) & 3, jh = f0 & 7;
            float4 bb = bias1[mi];
#pragma unroll
            for (int ni = 0; ni < 4; ++ni) {
                int edge = ni * 16 + lcol;
                float v0 = acc[mi][ni][0] + bb.x;
                float v1 = acc[mi][ni][1] + bb.y;
                float v2 = acc[mi][ni][2] + bb.z;
                float v3 = acc[mi][ni][3] + bb.w;
                bf16x4_t h = { (__bf16)fmaxf(v0, 0.f), (__bf16)fmaxf(v1, 0.f),
                               (__bf16)fmaxf(v2, 0.f), (__bf16)fmaxf(v3, 0.f) };
                *(bf16x4_t*)(ldsH + (size_t)((ktp * 4 + qrp) * 64 + edge) * 8 + jh) = h;
            }
        }
        __syncthreads();   // barrier B: ldsH ready

        // ---- prefetch next tile's sender fragments (drains during GEMM2) ----
        bf16x8_t sfn[4][4];
#pragma unroll
        for (int ni = 0; ni < 4; ++ni)
#pragma unroll
            for (int c = 0; c < 4; ++c)
                sfn[ni][c] = *(const bf16x8_t*)(nfb + (size_t)nsidx[ni] * CIN + c * 32 + qrow * 8);

        // ---- GEMM2 (unswapped): D = H · W2slice ; pure LDS + registers ----
        f32x4_t acc2[4][4];
#pragma unroll
        for (int mi = 0; mi < 4; ++mi)
#pragma unroll
            for (int ni = 0; ni < 4; ++ni)
                acc2[mi][ni] = (f32x4_t){0.f, 0.f, 0.f, 0.f};
#pragma unroll
        for (int kt = 0; kt < 8; ++kt) {
            bf16x8_t af[4];
#pragma unroll
            for (int mi = 0; mi < 4; ++mi)
                af[mi] = *(const bf16x8_t*)(ldsH +
                    (size_t)((kt * 4 + qrow) * 64 + mi * 16 + lcol) * 8);
#pragma unroll
            for (int mi = 0; mi < 4; ++mi)
#pragma unroll
                for (int ni = 0; ni < 4; ++ni)
                    acc2[mi][ni] = __builtin_amdgcn_mfma_f32_16x16x32_bf16(
                        af[mi], w2f[kt][ni], acc2[mi][ni], 0, 0, 0);
        }

        // ---- epilogue 2: per-node max over 32 edge rows, +b2, store ----
#pragma unroll
        for (int ni = 0; ni < 4; ++ni) {
            int col = wave * 64 + ni * 16 + lcol;
#pragma unroll
            for (int nd = 0; nd < 2; ++nd) {
                float mx = -3.402823466e38f;
#pragma unroll
                for (int h = 0; h < 2; ++h)
#pragma unroll
                    for (int r = 0; r < 4; ++r)
                        mx = fmaxf(mx, acc2[nd * 2 + h][ni][r]);
                mx = fmaxf(mx, __shfl_xor(mx, 16, 64));
                mx = fmaxf(mx, __shfl_xor(mx, 32, 64));
                if (qrow == 0)
                    out[(size_t)(node0 + nd) * HD + col] = mx + bias2[ni];
            }
        }

        // rotate prefetch
#pragma unroll
        for (int ni = 0; ni < 4; ++ni) {
            sidx[ni] = nsidx[ni];
#pragma unroll
            for (int c = 0; c < 4; ++c)
                sf[ni][c] = sfn[ni][c];
        }
    }
}

extern "C" void kernel_launch(void* const* d_in, const int* in_sizes, int n_in,
                              void* d_out, int out_size, void* d_ws, size_t ws_size,
                              hipStream_t stream) {
    const float* nf      = (const float*)d_in[0];
    const int*   senders = (const int*)d_in[1];
    // d_in[2] = receivers: implicit (repeat(arange(N), K)), unused
    const float* W1 = (const float*)d_in[3];
    const float* b1 = (const float*)d_in[4];
    const float* W2 = (const float*)d_in[5];
    const float* b2 = (const float*)d_in[6];

    __bf16* w1g = (__bf16*)d_ws;                 // 128 KB frag-ordered W1'
    __bf16* w2t = w1g + 256 * 256;               // 128 KB
    __bf16* nfb = w2t + 256 * 256;               // 5.12 MB bf16 node features

    ec_prep<<<(NN * CIN) / 256 + 256, 256, 0, stream>>>(nf, W1, W2, nfb, w1g, w2t);
    ec_main<<<NBLK, 256, 0, stream>>>(nfb, senders, w1g, w2t, b1, b2, (float*)d_out);
}